// Round 14
// baseline (748.629 us; speedup 1.0000x reference)
//
#include <hip/hip_runtime.h>

#define B_    1024
#define TI_   2
#define TE_   3
#define AB_   (TI_ * TE_)
#define BIN_  16
#define BOUT_ 32

typedef float f4 __attribute__((ext_vector_type(4)));

// ---------------------------------------------------------------------------
// R14: DIAGNOSTIC ROUND. R7/R8/R9 (three disjoint structures) tie at ~150us;
// every single-lever change regresses; pipe arithmetic underpredicts 2x. We
// have never seen our kernels' counters (fillBuffer poisons clog top-5).
// Two probes sized >270us to surface in top-5 with full PMC rows:
//   1) calib_store: pure float4 grid-stride store of the whole 444MB output,
//      x5 reps -> the TRUE achievable store BW for this buffer/harness.
//      Launched FIRST; real kernels overwrite -> final output correct.
//   2) conv_rep<...,REPEAT=8> on l8: byte-identical R9 kernel, 8x in-kernel
//      repeat (asm memory barrier per rep -> X/W genuinely reloaded; each
//      rep's 227MB store stream flushes L2 so reps stay representative).
//      Idempotent -> correct output.
// Readout plan: calib BW ~6.5TB/s => ceiling real & l8 inefficiency is ours;
// ~3TB/s => environmental write ceiling (we were near-roofline at 150).
// l8 FETCH/rep ~7MB => no RFO; ~227MB/rep => RFO. VALUBusy >70 => issue-
// bound; <30 => latency-bound. Occupancy row = actual waves/CU.
// ---------------------------------------------------------------------------

// pure-store calibration kernel (the fillBuffer analog we control)
__global__ __launch_bounds__(256)
void calib_store(float* __restrict__ OUT, int nq) {
    const int stride = gridDim.x * 256;
    const f4 z = {0.f, 0.f, 0.f, 0.f};
    for (int r = 0; r < 5; ++r) {
        asm volatile("" ::: "memory");
        for (int i = blockIdx.x * 256 + threadIdx.x; i < nq; i += stride)
            ((f4*)OUT)[i] = z;
    }
}

// R9 structure, unchanged, plus an outer repeat loop for diagnostics.
template<int NSH, int QTP, int SPB, int BLOCK, int REPEAT>
__global__ __launch_bounds__(BLOCK)
void conv_rep(const float* __restrict__ X, const float* __restrict__ W,
              float* __restrict__ OUT) {
    constexpr int TS   = 32 * QTP;        // threads per slice (wave multiple)
    constexpr int SZ   = BIN_ * NSH;      // X floats per slice
    constexpr int XR   = (SZ + 63) / 64;  // wave-spread X VGPRs
    constexpr int NOUT = BOUT_ * NSH * NSH;
    static_assert(SPB * TS == BLOCK, "geometry");
    static_assert(TS % 64 == 0, "wave-aligned slices");

    const int tid  = threadIdx.x;
    const int lane = tid & 63;
    const int sl   = tid / TS;            // wave-uniform
    const int wid  = tid - sl * TS;
    const int o    = wid / QTP;
    const int q    = wid - o * QTP;
    const int k0   = (4 * q > NSH - 4) ? (NSH - 4) : (4 * q);
    const int slice = blockIdx.x * SPB + sl;
    const int ab    = slice % AB_;

    for (int rep = 0; rep < REPEAT; ++rep) {
        asm volatile("" ::: "memory");   // force real reloads every rep

        // ---- X row-set into wave-spread VGPRs (coalesced) ----
        const float* Xs = X + (size_t)slice * SZ;
        float xr[XR];
#pragma unroll
        for (int c = 0; c < XR; ++c) {
            int idx = c * 64 + lane;
            if (idx > SZ - 1) idx = SZ - 1;
            xr[c] = Xs[idx];
        }

        // ---- hoist W (this thread's k-quad, all i) ----
        const float* Wp = W + (size_t)ab * (BIN_ * BOUT_ * NSH) + o * NSH + k0;
        f4 wreg[BIN_];
#pragma unroll
        for (int i = 0; i < BIN_; ++i)
            __builtin_memcpy(&wreg[i], Wp + (size_t)i * (BOUT_ * NSH), 16);

        f4 acc[NSH];
#pragma unroll
        for (int l = 0; l < NSH; ++l) acc[l] = (f4){0.f, 0.f, 0.f, 0.f};

#pragma unroll
        for (int i = 0; i < BIN_; ++i) {
#pragma unroll
            for (int l = 0; l < NSH; ++l) {
                const int idx = i * NSH + l;                    // compile-time
                const float xv = __int_as_float(
                    __builtin_amdgcn_readlane(__float_as_int(xr[idx >> 6]),
                                              idx & 63));
                const f4 xb = {xv, xv, xv, xv};
                acc[l] = __builtin_elementwise_fma(xb, wreg[i], acc[l]);
            }
        }

        // ---- direct 16B stores (dup quads store identical bytes) ----
        float* Op = OUT + (size_t)slice * NOUT + o * (NSH * NSH) + k0;
#pragma unroll
        for (int l = 0; l < NSH; ++l)
            __builtin_memcpy(Op + l * NSH, &acc[l], 16);
    }
}

// l=0: direct coalesced stores, 64 n per block.
__global__ __launch_bounds__(256)
void conv_l0_kernel(const float* __restrict__ X, const float* __restrict__ W,
                    const float* __restrict__ bias, float* __restrict__ OUT) {
    const int o  = threadIdx.x & 31;
    const int ns = threadIdx.x >> 5;   // 0..7
    const int b  = blockIdx.x;
    const int n0 = (b / AB_) * 64;
    const int ab = b % AB_;
    float wv[BIN_];
#pragma unroll
    for (int i = 0; i < BIN_; ++i) wv[i] = W[(ab * BIN_ + i) * BOUT_ + o];
    const float bv = bias[ab * BOUT_ + o];
#pragma unroll
    for (int s = 0; s < 8; ++s) {
        const int n = n0 + ns + s * 8;
        const float* Xp = X + ((size_t)n * AB_ + ab) * BIN_;
        float acc = bv;
#pragma unroll
        for (int i = 0; i < BIN_; ++i) acc = fmaf(Xp[i], wv[i], acc);
        OUT[((size_t)n * AB_ + ab) * BOUT_ + o] = acc;
    }
}

extern "C" void kernel_launch(void* const* d_in, const int* in_sizes, int n_in,
                              void* d_out, int out_size, void* d_ws, size_t ws_size,
                              hipStream_t stream) {
    const float* x0 = (const float*)d_in[0];
    const float* w0 = (const float*)d_in[1];
    const float* x2 = (const float*)d_in[2];
    const float* w2 = (const float*)d_in[3];
    const float* x4 = (const float*)d_in[4];
    const float* w4 = (const float*)d_in[5];
    const float* x6 = (const float*)d_in[6];
    const float* w6 = (const float*)d_in[7];
    const float* x8 = (const float*)d_in[8];
    const float* w8 = (const float*)d_in[9];
    const float* bias = (const float*)d_in[10];
    float* out = (float*)d_out;

    const size_t per = (size_t)B_ * AB_ * BOUT_;
    size_t off0 = 0;
    size_t off2 = off0 + per * 1;
    size_t off4 = off2 + per * 25;
    size_t off6 = off4 + per * 81;
    size_t off8 = off6 + per * 169;

    const int S = B_ * AB_;  // 6144 slices

    // 1) store-BW calibration over the entire output (overwritten below)
    calib_store<<<2048, 256, 0, stream>>>(out, out_size / 4);

    // 2) l8 diagnostic: R9 kernel x8 in-kernel repeats (idempotent)
    conv_rep<17, 6, 2, 384, 8><<<S / 2, 384, 0, stream>>>(x8, w8, out + off8);

    // 3) remaining degrees: R9 exact (REPEAT=1)
    conv_rep<13, 4, 2, 256, 1><<<S / 2, 256, 0, stream>>>(x6, w6, out + off6);
    conv_rep< 9, 4, 2, 256, 1><<<S / 2, 256, 0, stream>>>(x4, w4, out + off4);
    conv_rep< 5, 2, 8, 512, 1><<<S / 8, 512, 0, stream>>>(x2, w2, out + off2);
    conv_l0_kernel<<<(B_ / 64) * AB_, 256, 0, stream>>>(x0, w0, bias, out + off0);
}

// Round 15
// 148.882 us; speedup vs baseline: 5.0283x; 5.0283x over previous
//
#include <hip/hip_runtime.h>

#define B_    1024
#define TI_   2
#define TE_   3
#define AB_   (TI_ * TE_)
#define BIN_  16
#define BOUT_ 32

typedef float f4 __attribute__((ext_vector_type(4)));

// out[slice, o, l, k] = sum_i X[slice, i, l] * W[ab, i, o, k]
//
// R15 = R9 body EXACTLY, one lever changed: SPB (slices/block) raised so
// blocks are 2-6x fatter and block count drops 10,080 -> 4,128.
//
// R14 diagnostic: no RFO (FETCH 6.6MB vs 197MB/rep written), WRITE ideal,
// calib pure-store >=5.3TB/s, yet l8 body = 4.4TB/s with VALUBusy 52% and
// Occupancy 25% -- concurrency-starved, not pipe-bound. Sum of bodies
// ~105us vs 152.7 measured -> ~45us in launch/dispatch ramps of 10k tiny
// blocks. Fatter blocks amortize CP dispatch and keep CUs populated.
//
// Body (unchanged): thread = (slice, o, k-quad); X row-set wave-spread in
// <=5 VGPRs + compile-time v_readlane; W hoisted 16xf4; acc[NSH] f4 stored
// directly as 16B stores; tail quads overlap (k0=min(4q,NSH-4)), duplicate
// threads store identical bytes (benign; L2 merges, proven R14).
template<int NSH, int QTP, int SPB, int BLOCK>
__global__ __launch_bounds__(BLOCK)
void conv_fat(const float* __restrict__ X, const float* __restrict__ W,
              float* __restrict__ OUT) {
    constexpr int TS   = 32 * QTP;        // threads per slice (wave multiple)
    constexpr int SZ   = BIN_ * NSH;      // X floats per slice
    constexpr int XR   = (SZ + 63) / 64;  // wave-spread X VGPRs
    constexpr int NOUT = BOUT_ * NSH * NSH;
    static_assert(SPB * TS == BLOCK, "geometry");
    static_assert(TS % 64 == 0, "wave-aligned slices");

    const int tid  = threadIdx.x;
    const int lane = tid & 63;
    const int sl   = tid / TS;            // wave-uniform
    const int wid  = tid - sl * TS;
    const int o    = wid / QTP;
    const int q    = wid - o * QTP;
    const int k0   = (4 * q > NSH - 4) ? (NSH - 4) : (4 * q);
    const int slice = blockIdx.x * SPB + sl;
    const int ab    = slice % AB_;

    // ---- X row-set into wave-spread VGPRs (coalesced; clamped tail slots
    //      are never readlane'd) ----
    const float* Xs = X + (size_t)slice * SZ;
    float xr[XR];
#pragma unroll
    for (int c = 0; c < XR; ++c) {
        int idx = c * 64 + lane;
        if (idx > SZ - 1) idx = SZ - 1;
        xr[c] = Xs[idx];
    }

    // ---- hoist W (this thread's k-quad, all i); 16B loads, 4B-aligned ok ----
    const float* Wp = W + (size_t)ab * (BIN_ * BOUT_ * NSH) + o * NSH + k0;
    f4 wreg[BIN_];
#pragma unroll
    for (int i = 0; i < BIN_; ++i)
        __builtin_memcpy(&wreg[i], Wp + (size_t)i * (BOUT_ * NSH), 16);

    f4 acc[NSH];
#pragma unroll
    for (int l = 0; l < NSH; ++l) acc[l] = (f4){0.f, 0.f, 0.f, 0.f};

#pragma unroll
    for (int i = 0; i < BIN_; ++i) {
#pragma unroll
        for (int l = 0; l < NSH; ++l) {
            const int idx = i * NSH + l;                    // compile-time
            const float xv = __int_as_float(
                __builtin_amdgcn_readlane(__float_as_int(xr[idx >> 6]),
                                          idx & 63));
            const f4 xb = {xv, xv, xv, xv};
            acc[l] = __builtin_elementwise_fma(xb, wreg[i], acc[l]);
        }
    }

    // ---- direct 16B stores (dup quads store identical bytes; benign) ----
    float* Op = OUT + (size_t)slice * NOUT + o * (NSH * NSH) + k0;
#pragma unroll
    for (int l = 0; l < NSH; ++l)
        __builtin_memcpy(Op + l * NSH, &acc[l], 16);
}

// l=0: direct coalesced stores, 64 n per block.
__global__ __launch_bounds__(256)
void conv_l0_kernel(const float* __restrict__ X, const float* __restrict__ W,
                    const float* __restrict__ bias, float* __restrict__ OUT) {
    const int o  = threadIdx.x & 31;
    const int ns = threadIdx.x >> 5;   // 0..7
    const int b  = blockIdx.x;
    const int n0 = (b / AB_) * 64;
    const int ab = b % AB_;
    float wv[BIN_];
#pragma unroll
    for (int i = 0; i < BIN_; ++i) wv[i] = W[(ab * BIN_ + i) * BOUT_ + o];
    const float bv = bias[ab * BOUT_ + o];
#pragma unroll
    for (int s = 0; s < 8; ++s) {
        const int n = n0 + ns + s * 8;
        const float* Xp = X + ((size_t)n * AB_ + ab) * BIN_;
        float acc = bv;
#pragma unroll
        for (int i = 0; i < BIN_; ++i) acc = fmaf(Xp[i], wv[i], acc);
        OUT[((size_t)n * AB_ + ab) * BOUT_ + o] = acc;
    }
}

extern "C" void kernel_launch(void* const* d_in, const int* in_sizes, int n_in,
                              void* d_out, int out_size, void* d_ws, size_t ws_size,
                              hipStream_t stream) {
    const float* x0 = (const float*)d_in[0];
    const float* w0 = (const float*)d_in[1];
    const float* x2 = (const float*)d_in[2];
    const float* w2 = (const float*)d_in[3];
    const float* x4 = (const float*)d_in[4];
    const float* w4 = (const float*)d_in[5];
    const float* x6 = (const float*)d_in[6];
    const float* w6 = (const float*)d_in[7];
    const float* x8 = (const float*)d_in[8];
    const float* w8 = (const float*)d_in[9];
    const float* bias = (const float*)d_in[10];
    float* out = (float*)d_out;

    const size_t per = (size_t)B_ * AB_ * BOUT_;
    size_t off0 = 0;
    size_t off2 = off0 + per * 1;
    size_t off4 = off2 + per * 25;
    size_t off6 = off4 + per * 81;
    size_t off8 = off6 + per * 169;

    const int S = B_ * AB_;  // 6144 slices

    //        NSH QTP SPB BLOCK           grid    blocks: 1536/1024/1024/512/96
    conv_fat<17, 6,  4, 768><<<S / 4,  768, 0, stream>>>(x8, w8, out + off8);
    conv_fat<13, 4,  6, 768><<<S / 6,  768, 0, stream>>>(x6, w6, out + off6);
    conv_fat< 9, 4,  6, 768><<<S / 6,  768, 0, stream>>>(x4, w4, out + off4);
    conv_fat< 5, 2, 12, 768><<<S / 12, 768, 0, stream>>>(x2, w2, out + off2);
    conv_l0_kernel<<<(B_ / 64) * AB_, 256, 0, stream>>>(x0, w0, bias, out + off0);
}